// Round 6
// baseline (1920.066 us; speedup 1.0000x reference)
//
#include <hip/hip_runtime.h>
#include <hip/hip_bf16.h>
#include <stdint.h>

#define TOK  4096
#define DIM  2048
#define HID  4096
#define ODIM 2048
#define NEXP 8
#define KSEL 5

typedef __bf16 bf16x8 __attribute__((ext_vector_type(8)));
typedef float  f32x4  __attribute__((ext_vector_type(4)));
typedef unsigned short ushort8 __attribute__((ext_vector_type(8)));

__device__ __forceinline__ uint16_t f2bf(float f) {
  uint32_t u = __float_as_uint(f);
  u += 0x7FFFu + ((u >> 16) & 1u);   // round-to-nearest-even
  return (uint16_t)(u >> 16);
}
__device__ __forceinline__ float bf2f(uint16_t h) {
  uint32_t u = ((uint32_t)h) << 16;
  return __uint_as_float(u);
}

#define GLD16(g, l) __builtin_amdgcn_global_load_lds(                      \
    (const __attribute__((address_space(1))) void*)(g),                    \
    (__attribute__((address_space(3))) void*)(l), 16, 0, 0)

// ---------------- convert kernels ----------------

__global__ void cast_x_kernel(const float* __restrict__ in,
                              uint16_t* __restrict__ out, int n4) {
  int i = blockIdx.x * blockDim.x + threadIdx.x;
  if (i >= n4) return;
  float4 v = ((const float4*)in)[i];
  ushort4 o;
  o.x = f2bf(v.x); o.y = f2bf(v.y); o.z = f2bf(v.z); o.w = f2bf(v.w);
  ((ushort4*)out)[i] = o;
}

// out[c*R + r] = bf16(in[r*C + c]), batched over blockIdx.z
__global__ void transpose_cast_kernel(const float* __restrict__ in,
                                      uint16_t* __restrict__ out,
                                      int R, int C, long inBatch, long outBatch) {
  __shared__ float tile[32][33];
  const float* src = in + (size_t)blockIdx.z * inBatch;
  uint16_t*    dst = out + (size_t)blockIdx.z * outBatch;
  int c0 = blockIdx.x * 32, r0 = blockIdx.y * 32;
  int tx = threadIdx.x, ty = threadIdx.y;   // (32, 8)
#pragma unroll
  for (int i = 0; i < 4; ++i)
    tile[ty + i * 8][tx] = src[(size_t)(r0 + ty + i * 8) * C + c0 + tx];
  __syncthreads();
#pragma unroll
  for (int i = 0; i < 4; ++i)
    dst[(size_t)(c0 + ty + i * 8) * R + r0 + tx] = f2bf(tile[tx][ty + i * 8]);
}

// ---------------- routing: weights + selection bitmask (pure, no atomics) ----------------

__global__ void routing_kernel(const float* __restrict__ x,
                               const float* __restrict__ Wg, const float* __restrict__ bg,
                               const float* __restrict__ Wa, const float* __restrict__ ba,
                               const float* __restrict__ Wb, const float* __restrict__ bb,
                               const float* __restrict__ sigs,
                               float* __restrict__ wts, int* __restrict__ selmask_g) {
  const int n    = blockIdx.x;
  const int lane = threadIdx.x;   // 64
  const float* xr = x + (size_t)n * DIM;

  float ga[NEXP]; float aa[32];
#pragma unroll
  for (int e = 0; e < NEXP; ++e) ga[e] = 0.f;
#pragma unroll
  for (int j = 0; j < 32; ++j) aa[j] = 0.f;

  for (int it = 0; it < DIM / 64; ++it) {
    int d = it * 64 + lane;
    float xv = xr[d];
    const float* wgr = Wg + (size_t)d * NEXP;
#pragma unroll
    for (int e = 0; e < NEXP; ++e) ga[e] += xv * wgr[e];
    const float* war = Wa + (size_t)d * 32;
#pragma unroll
    for (int j = 0; j < 32; ++j) aa[j] += xv * war[j];
  }
#pragma unroll
  for (int s = 1; s < 64; s <<= 1) {
#pragma unroll
    for (int e = 0; e < NEXP; ++e) ga[e] += __shfl_xor(ga[e], s);
#pragma unroll
    for (int j = 0; j < 32; ++j) aa[j] += __shfl_xor(aa[j], s);
  }

  float ph[16];
#pragma unroll
  for (int i = 0; i < 16; ++i) ph[i] = bb[i];
#pragma unroll
  for (int j = 0; j < 32; ++j) {
    float a = aa[j] + ba[j];
    a = a > 0.f ? a : 0.f;
#pragma unroll
    for (int i = 0; i < 16; ++i) ph[i] += a * Wb[j * 16 + i];
  }
  float nrm = 0.f;
#pragma unroll
  for (int i = 0; i < 16; ++i) nrm += ph[i] * ph[i];
  nrm = fmaxf(sqrtf(nrm), 1e-12f);

  const float invT = 0.36787944117144233f;  // 1/e
  float lg[NEXP], mx = -1e30f;
#pragma unroll
  for (int e = 0; e < NEXP; ++e) { lg[e] = (ga[e] + bg[e]) * invT; mx = fmaxf(mx, lg[e]); }
  float psum = 0.f, pr[NEXP];
#pragma unroll
  for (int e = 0; e < NEXP; ++e) { pr[e] = expf(lg[e] - mx); psum += pr[e]; }

  float eff[NEXP];
#pragma unroll
  for (int e = 0; e < NEXP; ++e) {
    const float* sg = sigs + e * 16;
    float dot = 0.f, sn = 0.f;
#pragma unroll
    for (int i = 0; i < 16; ++i) { dot += ph[i] * sg[i]; sn += sg[i] * sg[i]; }
    sn = fmaxf(sqrtf(sn), 1e-12f);
    float match = (dot / (nrm * sn) + 1.f) * 0.5f;
    eff[e] = (pr[e] / psum) * match;
  }

  int selmask = 0;
#pragma unroll
  for (int t = 0; t < KSEL; ++t) {
    int bi = 0; float bv = -1e30f;
#pragma unroll
    for (int e = 0; e < NEXP; ++e) {
      bool ok = !((selmask >> e) & 1);
      if (ok && eff[e] > bv) { bv = eff[e]; bi = e; }
    }
    selmask |= (1 << bi);
  }
  float wsum = 0.f, wv[NEXP];
#pragma unroll
  for (int e = 0; e < NEXP; ++e) {
    wv[e] = ((selmask >> e) & 1) ? eff[e] : 0.f;
    wsum += wv[e];
  }
  float inv = 1.f / (wsum + 1e-8f);
  if (lane == 0) {
#pragma unroll
    for (int e = 0; e < NEXP; ++e) wts[n * NEXP + e] = wv[e] * inv;
    selmask_g[n] = selmask;
  }
}

// ---------------- deterministic sorted list build (1 block per expert) ----------------

__global__ void listbuild_kernel(const int* __restrict__ selmask_g,
                                 const float* __restrict__ wts,
                                 int* __restrict__ cnt, int* __restrict__ base,
                                 int* __restrict__ list, int* __restrict__ slot_map,
                                 float* __restrict__ wrow) {
  const int e = blockIdx.x;      // 0..7
  const int t = threadIdx.x;     // 0..255, each owns 16 consecutive tokens
  __shared__ int cntT[256][NEXP];
  __shared__ int totAll[NEXP];
  __shared__ int sc[256];

  int msk[16];
  int c8[NEXP];
#pragma unroll
  for (int f = 0; f < NEXP; ++f) c8[f] = 0;
#pragma unroll
  for (int i = 0; i < 16; ++i) {
    msk[i] = selmask_g[t * 16 + i];
#pragma unroll
    for (int f = 0; f < NEXP; ++f) c8[f] += (msk[i] >> f) & 1;
  }
#pragma unroll
  for (int f = 0; f < NEXP; ++f) cntT[t][f] = c8[f];
  __syncthreads();

  if (t < NEXP) {
    int s = 0;
    for (int j = 0; j < 256; ++j) s += cntT[j][t];
    totAll[t] = s;
  }
  __syncthreads();

  if (e == 0 && t == 0) {
    int r = 0;
    for (int f = 0; f < NEXP; ++f) { cnt[f] = totAll[f]; base[f] = r; r += totAll[f]; }
  }
  int gbase = 0;
  for (int f = 0; f < e; ++f) gbase += totAll[f];

  // exclusive prefix over threads for expert e
  sc[t] = c8[e];
  __syncthreads();
  for (int off = 1; off < 256; off <<= 1) {
    int v = (t >= off) ? sc[t - off] : 0;
    __syncthreads();
    sc[t] += v;
    __syncthreads();
  }
  int p = sc[t] - c8[e];

#pragma unroll
  for (int i = 0; i < 16; ++i) {
    const int n = t * 16 + i;
    const int m = msk[i];
    if ((m >> e) & 1) {
      list[e * TOK + p] = n;
      const int rank = __popc(m & ((1 << e) - 1));
      slot_map[n * KSEL + rank] = gbase + p;
      wrow[gbase + p] = wts[n * NEXP + e];
      ++p;
    }
  }
}

// ---------------- pipelined GEMM (BM=BN=128, BK=32, 4 waves, 4 LDS slots, 2 blocks/CU) ----
// A [rows, Kdim] bf16 (MODE1: gathered via list; MODE2: compact), Bt [E][Ncols][Kdim] bf16.
// LDS slot (16 KB): A granules (g*128+row)*8 for g<4 (8 KB), then B likewise (8 KB).
// Schedule: compute tile T from slot T&3; during T issue stage for T+3 into slot (T+3)&3
// = (T-1)&3 (readers of that slot drained their ds_reads at T-1's lgkmcnt(0), and the
// T-top barrier orders them before these writes).  ONE barrier per K-tile.
// Waits: vmcnt(8) at tile top (T+1,T+2's 8 GLDs remain in flight); 4/0 at the tail.

template <int MODE>
__launch_bounds__(256, 2)
__global__ void gemm_pipe_kernel(const uint16_t* __restrict__ A,
                                 const uint16_t* __restrict__ Bt,
                                 const int* __restrict__ cnt,
                                 const int* __restrict__ base,
                                 const int* __restrict__ list,
                                 const float* __restrict__ wrow,
                                 const float* __restrict__ bias,
                                 uint16_t* __restrict__ outb,
                                 int Kdim, int NTk, int Ncols) {
  __shared__ __attribute__((aligned(16))) uint16_t lds[4 * 8192];  // 64 KiB, 4 slots

  const int e  = blockIdx.z;
  const int ce = cnt[e];
  const int tileM = blockIdx.y * 128;
  if (tileM >= ce) return;
  const int be    = base[e];
  const int tileN = blockIdx.x * 128;
  const int tid = threadIdx.x, lane = tid & 63, wid = tid >> 6;
  const int wr = wid >> 1, wc = wid & 1;     // wave tile: 64 rows x 64 cols

  // staging: thread stages row (tid&127) of A and of B, granules g0=tid>>7 and g0+2
  const int srow = tid & 127;
  const int g0   = tid >> 7;
  int pA = tileM + srow; pA = pA < ce ? pA : ce - 1;
  const uint16_t* aRow;
  if (MODE == 1) aRow = A + (size_t)list[e * TOK + pA] * Kdim;
  else           aRow = A + (size_t)(be + pA) * Kdim;
  const uint16_t* bRow = Bt + ((size_t)e * Ncols + tileN + srow) * Kdim;

  // LDS dest byte bases (wave-uniform; HW adds lane*16)
  // granule f = g*128+row; thread's dests: f0 = g0*128+srow = tid, f1 = tid+256
  char* ldsb = (char*)lds;
  const uint32_t dA0 = (uint32_t)wid * 1024;          // + slot*16384
  const uint32_t dA1 = dA0 + 4096;
  const uint32_t dB0 = dA0 + 8192;
  const uint32_t dB1 = dA0 + 12288;

#define STAGE(slotIdx, kOff)                                              \
  { const uint32_t sb = (uint32_t)(slotIdx) * 16384;                      \
    GLD16(aRow + (kOff) + g0 * 8,       ldsb + sb + dA0);                 \
    GLD16(aRow + (kOff) + (g0 + 2) * 8, ldsb + sb + dA1);                 \
    GLD16(bRow + (kOff) + g0 * 8,       ldsb + sb + dB0);                 \
    GLD16(bRow + (kOff) + (g0 + 2) * 8, ldsb + sb + dB1); }

  // fragment elem offsets: granule (lane>>4)*128 + wr*64 + m*16 + (lane&15)
  const int afrag = ((lane >> 4) << 7) + wr * 64 + (lane & 15);
  const int bfrag = ((lane >> 4) << 7) + wc * 64 + (lane & 15);

  f32x4 acc[4][4];
#pragma unroll
  for (int m = 0; m < 4; ++m)
#pragma unroll
    for (int n = 0; n < 4; ++n) acc[m][n] = (f32x4){0.f, 0.f, 0.f, 0.f};

  // prologue: stage T0, T1, T2 (12 GLDs, FIFO oldest-first)
  STAGE(0, 0);
  STAGE(1, 32);
  STAGE(2, 64);

  for (int T = 0; T < NTk; ++T) {
    if (T + 2 < NTk)      asm volatile("s_waitcnt vmcnt(8)" ::: "memory");
    else if (T + 1 < NTk) asm volatile("s_waitcnt vmcnt(4)" ::: "memory");
    else                  asm volatile("s_waitcnt vmcnt(0)" ::: "memory");
    __builtin_amdgcn_sched_barrier(0);
    __builtin_amdgcn_s_barrier();

    const uint16_t* As = lds + (T & 3) * 8192;
    const uint16_t* Bs = As + 4096;

    bf16x8 av[4], bv[4];
#pragma unroll
    for (int m = 0; m < 4; ++m)
      av[m] = *(const bf16x8*)(As + (size_t)(afrag + m * 16) * 8);
#pragma unroll
    for (int n = 0; n < 4; ++n)
      bv[n] = *(const bf16x8*)(Bs + (size_t)(bfrag + n * 16) * 8);

    if (T + 3 < NTk) STAGE((T + 3) & 3, (T + 3) * 32);

    asm volatile("s_waitcnt lgkmcnt(0)" ::: "memory");
    __builtin_amdgcn_sched_barrier(0);
    __builtin_amdgcn_s_setprio(1);
#pragma unroll
    for (int m = 0; m < 4; ++m)
#pragma unroll
      for (int n = 0; n < 4; ++n)
        acc[m][n] = __builtin_amdgcn_mfma_f32_16x16x32_bf16(av[m], bv[n], acc[m][n], 0, 0, 0);
    __builtin_amdgcn_s_setprio(0);
  }
#undef STAGE

  // ---- epilogue ----
  if (MODE == 1) {
    const float* b1e = bias + (size_t)e * Ncols;
#pragma unroll
    for (int m = 0; m < 4; ++m)
#pragma unroll
      for (int r = 0; r < 4; ++r) {
        const int p = tileM + wr * 64 + m * 16 + ((lane >> 4) << 2) + r;
        if (p < ce) {
          const float w = wrow[be + p];
          uint16_t* orow = outb + (size_t)(be + p) * Ncols;
#pragma unroll
          for (int n = 0; n < 4; ++n) {
            const int col = tileN + wc * 64 + n * 16 + (lane & 15);
            float v = acc[m][n][r] + b1e[col];
            v = v > 0.f ? v : 0.f;
            orow[col] = f2bf(v * w);
          }
        }
      }
  } else {
#pragma unroll
    for (int m = 0; m < 4; ++m)
#pragma unroll
      for (int r = 0; r < 4; ++r) {
        const int p = tileM + wr * 64 + m * 16 + ((lane >> 4) << 2) + r;
        if (p < ce) {
          uint16_t* orow = outb + (size_t)(be + p) * Ncols;
#pragma unroll
          for (int n = 0; n < 4; ++n) {
            const int col = tileN + wc * 64 + n * 16 + (lane & 15);
            orow[col] = f2bf(acc[m][n][r]);
          }
        }
      }
  }
}

// ---------------- reduce: out[n,:] = sum_e w*b2[e,:] + sum_{k<5} obuf[slot_k,:] ----------------

__global__ void reduce_kernel(const uint16_t* __restrict__ obuf,
                              const int* __restrict__ slot_map,
                              const float* __restrict__ wts,
                              const float* __restrict__ b2,
                              float* __restrict__ out) {
  const int n = blockIdx.x;
  const int t = threadIdx.x;            // 256
  const int c = t * 8;                  // 8 cols per thread

  int slots[KSEL];
#pragma unroll
  for (int k = 0; k < KSEL; ++k) slots[k] = slot_map[n * KSEL + k];
  float w8[NEXP];
#pragma unroll
  for (int e = 0; e < NEXP; ++e) w8[e] = wts[n * NEXP + e];

  float s[8];
#pragma unroll
  for (int j = 0; j < 8; ++j) s[j] = 0.f;
#pragma unroll
  for (int e = 0; e < NEXP; ++e) {
    const float4 b0 = *(const float4*)(b2 + (size_t)e * ODIM + c);
    const float4 b1v = *(const float4*)(b2 + (size_t)e * ODIM + c + 4);
    s[0] += w8[e] * b0.x; s[1] += w8[e] * b0.y; s[2] += w8[e] * b0.z; s[3] += w8[e] * b0.w;
    s[4] += w8[e] * b1v.x; s[5] += w8[e] * b1v.y; s[6] += w8[e] * b1v.z; s[7] += w8[e] * b1v.w;
  }
#pragma unroll
  for (int k = 0; k < KSEL; ++k) {
    const ushort8 v = *(const ushort8*)(obuf + (size_t)slots[k] * ODIM + c);
#pragma unroll
    for (int j = 0; j < 8; ++j) s[j] += bf2f(v[j]);
  }
  float4 o0 = make_float4(s[0], s[1], s[2], s[3]);
  float4 o1 = make_float4(s[4], s[5], s[6], s[7]);
  *(float4*)(out + (size_t)n * ODIM + c) = o0;
  *(float4*)(out + (size_t)n * ODIM + c + 4) = o1;
}

// ---------------- launch ----------------

extern "C" void kernel_launch(void* const* d_in, const int* in_sizes, int n_in,
                              void* d_out, int out_size, void* d_ws, size_t ws_size,
                              hipStream_t stream) {
  const float* x    = (const float*)d_in[0];
  const float* Wg   = (const float*)d_in[1];
  const float* bg   = (const float*)d_in[2];
  const float* Wa   = (const float*)d_in[3];
  const float* ba   = (const float*)d_in[4];
  const float* Wb   = (const float*)d_in[5];
  const float* bb   = (const float*)d_in[6];
  const float* sigs = (const float*)d_in[7];
  const float* W1   = (const float*)d_in[8];
  const float* b1   = (const float*)d_in[9];
  const float* W2   = (const float*)d_in[10];
  const float* b2   = (const float*)d_in[11];
  float* out = (float*)d_out;

  char* ws = (char*)d_ws;
  float*    wts     = (float*)(ws + 0);           //   131072 B
  int*      selmask = (int*)(ws + 131072);        //    16384 B
  int*      cnt     = (int*)(ws + 147456);        //       32 B
  int*      base    = (int*)(ws + 147584);        //       32 B
  int*      slot_map= (int*)(ws + 151552);        //    81920 B
  float*    wrow    = (float*)(ws + 233472);      //    81920 B
  int*      list    = (int*)(ws + 315392);        //   131072 B -> 446464
  uint16_t* xbf     = (uint16_t*)(ws + 446464);   //  16777216 B -> 17223680
  uint16_t* W1T     = (uint16_t*)(ws + 17223680); // 134217728 B -> 151441408
  uint16_t* W2T     = (uint16_t*)(ws + 151441408);// 134217728 B -> 285659136
  uint16_t* hbuf    = (uint16_t*)(ws + 285659136);// 167772160 B -> 453431296
  uint16_t* obuf    = (uint16_t*)(ws + 453431296);//  83886080 B -> 537317376 (512.4 MB)

  cast_x_kernel<<<(TOK * DIM / 4) / 256, 256, 0, stream>>>(x, xbf, TOK * DIM / 4);
  // W1 [E][D][H] -> W1T [E][H][D]
  transpose_cast_kernel<<<dim3(HID / 32, DIM / 32, NEXP), dim3(32, 8), 0, stream>>>(
      W1, W1T, DIM, HID, (long)DIM * HID, (long)DIM * HID);
  // W2 [E][H][O] -> W2T [E][O][H]  (per-expert contiguous, 8KB B-row stride)
  transpose_cast_kernel<<<dim3(ODIM / 32, HID / 32, NEXP), dim3(32, 8), 0, stream>>>(
      W2, W2T, HID, ODIM, (long)HID * ODIM, (long)ODIM * HID);
  routing_kernel<<<TOK, 64, 0, stream>>>(x, Wg, bg, Wa, ba, Wb, bb, sigs, wts, selmask);
  listbuild_kernel<<<NEXP, 256, 0, stream>>>(selmask, wts, cnt, base, list, slot_map, wrow);

  // gemm1: hbuf[be+p, col] = bf16( wrow * relu( x[list[p],:] @ W1[e][:,col] + b1[e,col] ) )
  gemm_pipe_kernel<1><<<dim3(HID / 128, TOK / 128, NEXP), 256, 0, stream>>>(
      xbf, W1T, cnt, base, list, wrow, b1, hbuf, DIM, DIM / 32, HID);
  // gemm2: obuf[be+p, col] = bf16( hbuf[be+p, :] @ W2[e][:, col] )
  gemm_pipe_kernel<2><<<dim3(ODIM / 128, TOK / 128, NEXP), 256, 0, stream>>>(
      hbuf, W2T, cnt, base, nullptr, nullptr, nullptr, obuf, HID, HID / 32, ODIM);
  reduce_kernel<<<TOK, 256, 0, stream>>>(obuf, slot_map, wts, b2, out);
}

// Round 7
// 1565.657 us; speedup vs baseline: 1.2264x; 1.2264x over previous
//
#include <hip/hip_runtime.h>
#include <hip/hip_bf16.h>
#include <stdint.h>

#define TOK  4096
#define DIM  2048
#define HID  4096
#define ODIM 2048
#define NEXP 8
#define KSEL 5

typedef __bf16 bf16x8 __attribute__((ext_vector_type(8)));
typedef float  f32x4  __attribute__((ext_vector_type(4)));
typedef unsigned short ushort8 __attribute__((ext_vector_type(8)));

__device__ __forceinline__ uint16_t f2bf(float f) {
  uint32_t u = __float_as_uint(f);
  u += 0x7FFFu + ((u >> 16) & 1u);   // round-to-nearest-even
  return (uint16_t)(u >> 16);
}
__device__ __forceinline__ float bf2f(uint16_t h) {
  uint32_t u = ((uint32_t)h) << 16;
  return __uint_as_float(u);
}

#define GLD16(g, l) __builtin_amdgcn_global_load_lds(                      \
    (const __attribute__((address_space(1))) void*)(g),                    \
    (__attribute__((address_space(3))) void*)(l), 16, 0, 0)

// ---------------- convert kernels ----------------

__global__ void cast_x_kernel(const float* __restrict__ in,
                              uint16_t* __restrict__ out, int n4) {
  int i = blockIdx.x * blockDim.x + threadIdx.x;
  if (i >= n4) return;
  float4 v = ((const float4*)in)[i];
  ushort4 o;
  o.x = f2bf(v.x); o.y = f2bf(v.y); o.z = f2bf(v.z); o.w = f2bf(v.w);
  ((ushort4*)out)[i] = o;
}

// out[c*R + r] = bf16(in[r*C + c]), batched over blockIdx.z
__global__ void transpose_cast_kernel(const float* __restrict__ in,
                                      uint16_t* __restrict__ out,
                                      int R, int C, long inBatch, long outBatch) {
  __shared__ float tile[32][33];
  const float* src = in + (size_t)blockIdx.z * inBatch;
  uint16_t*    dst = out + (size_t)blockIdx.z * outBatch;
  int c0 = blockIdx.x * 32, r0 = blockIdx.y * 32;
  int tx = threadIdx.x, ty = threadIdx.y;   // (32, 8)
#pragma unroll
  for (int i = 0; i < 4; ++i)
    tile[ty + i * 8][tx] = src[(size_t)(r0 + ty + i * 8) * C + c0 + tx];
  __syncthreads();
#pragma unroll
  for (int i = 0; i < 4; ++i)
    dst[(size_t)(c0 + ty + i * 8) * R + r0 + tx] = f2bf(tile[tx][ty + i * 8]);
}

// ---------------- routing: weights + selection bitmask (pure, no atomics) ----------------

__global__ void routing_kernel(const float* __restrict__ x,
                               const float* __restrict__ Wg, const float* __restrict__ bg,
                               const float* __restrict__ Wa, const float* __restrict__ ba,
                               const float* __restrict__ Wb, const float* __restrict__ bb,
                               const float* __restrict__ sigs,
                               float* __restrict__ wts, int* __restrict__ selmask_g) {
  const int n    = blockIdx.x;
  const int lane = threadIdx.x;   // 64
  const float* xr = x + (size_t)n * DIM;

  float ga[NEXP]; float aa[32];
#pragma unroll
  for (int e = 0; e < NEXP; ++e) ga[e] = 0.f;
#pragma unroll
  for (int j = 0; j < 32; ++j) aa[j] = 0.f;

  for (int it = 0; it < DIM / 64; ++it) {
    int d = it * 64 + lane;
    float xv = xr[d];
    const float* wgr = Wg + (size_t)d * NEXP;
#pragma unroll
    for (int e = 0; e < NEXP; ++e) ga[e] += xv * wgr[e];
    const float* war = Wa + (size_t)d * 32;
#pragma unroll
    for (int j = 0; j < 32; ++j) aa[j] += xv * war[j];
  }
#pragma unroll
  for (int s = 1; s < 64; s <<= 1) {
#pragma unroll
    for (int e = 0; e < NEXP; ++e) ga[e] += __shfl_xor(ga[e], s);
#pragma unroll
    for (int j = 0; j < 32; ++j) aa[j] += __shfl_xor(aa[j], s);
  }

  float ph[16];
#pragma unroll
  for (int i = 0; i < 16; ++i) ph[i] = bb[i];
#pragma unroll
  for (int j = 0; j < 32; ++j) {
    float a = aa[j] + ba[j];
    a = a > 0.f ? a : 0.f;
#pragma unroll
    for (int i = 0; i < 16; ++i) ph[i] += a * Wb[j * 16 + i];
  }
  float nrm = 0.f;
#pragma unroll
  for (int i = 0; i < 16; ++i) nrm += ph[i] * ph[i];
  nrm = fmaxf(sqrtf(nrm), 1e-12f);

  const float invT = 0.36787944117144233f;  // 1/e
  float lg[NEXP], mx = -1e30f;
#pragma unroll
  for (int e = 0; e < NEXP; ++e) { lg[e] = (ga[e] + bg[e]) * invT; mx = fmaxf(mx, lg[e]); }
  float psum = 0.f, pr[NEXP];
#pragma unroll
  for (int e = 0; e < NEXP; ++e) { pr[e] = expf(lg[e] - mx); psum += pr[e]; }

  float eff[NEXP];
#pragma unroll
  for (int e = 0; e < NEXP; ++e) {
    const float* sg = sigs + e * 16;
    float dot = 0.f, sn = 0.f;
#pragma unroll
    for (int i = 0; i < 16; ++i) { dot += ph[i] * sg[i]; sn += sg[i] * sg[i]; }
    sn = fmaxf(sqrtf(sn), 1e-12f);
    float match = (dot / (nrm * sn) + 1.f) * 0.5f;
    eff[e] = (pr[e] / psum) * match;
  }

  int selmask = 0;
#pragma unroll
  for (int t = 0; t < KSEL; ++t) {
    int bi = 0; float bv = -1e30f;
#pragma unroll
    for (int e = 0; e < NEXP; ++e) {
      bool ok = !((selmask >> e) & 1);
      if (ok && eff[e] > bv) { bv = eff[e]; bi = e; }
    }
    selmask |= (1 << bi);
  }
  float wsum = 0.f, wv[NEXP];
#pragma unroll
  for (int e = 0; e < NEXP; ++e) {
    wv[e] = ((selmask >> e) & 1) ? eff[e] : 0.f;
    wsum += wv[e];
  }
  float inv = 1.f / (wsum + 1e-8f);
  if (lane == 0) {
#pragma unroll
    for (int e = 0; e < NEXP; ++e) wts[n * NEXP + e] = wv[e] * inv;
    selmask_g[n] = selmask;
  }
}

// ---------------- deterministic sorted list build (1 block per expert) ----------------

__global__ void listbuild_kernel(const int* __restrict__ selmask_g,
                                 const float* __restrict__ wts,
                                 int* __restrict__ cnt, int* __restrict__ base,
                                 int* __restrict__ list, int* __restrict__ slot_map,
                                 float* __restrict__ wrow) {
  const int e = blockIdx.x;      // 0..7
  const int t = threadIdx.x;     // 0..255, each owns 16 consecutive tokens
  __shared__ int cntT[256][NEXP];
  __shared__ int totAll[NEXP];
  __shared__ int sc[256];

  int msk[16];
  int c8[NEXP];
#pragma unroll
  for (int f = 0; f < NEXP; ++f) c8[f] = 0;
#pragma unroll
  for (int i = 0; i < 16; ++i) {
    msk[i] = selmask_g[t * 16 + i];
#pragma unroll
    for (int f = 0; f < NEXP; ++f) c8[f] += (msk[i] >> f) & 1;
  }
#pragma unroll
  for (int f = 0; f < NEXP; ++f) cntT[t][f] = c8[f];
  __syncthreads();

  if (t < NEXP) {
    int s = 0;
    for (int j = 0; j < 256; ++j) s += cntT[j][t];
    totAll[t] = s;
  }
  __syncthreads();

  if (e == 0 && t == 0) {
    int r = 0;
    for (int f = 0; f < NEXP; ++f) { cnt[f] = totAll[f]; base[f] = r; r += totAll[f]; }
  }
  int gbase = 0;
  for (int f = 0; f < e; ++f) gbase += totAll[f];

  // exclusive prefix over threads for expert e
  sc[t] = c8[e];
  __syncthreads();
  for (int off = 1; off < 256; off <<= 1) {
    int v = (t >= off) ? sc[t - off] : 0;
    __syncthreads();
    sc[t] += v;
    __syncthreads();
  }
  int p = sc[t] - c8[e];

#pragma unroll
  for (int i = 0; i < 16; ++i) {
    const int n = t * 16 + i;
    const int m = msk[i];
    if ((m >> e) & 1) {
      list[e * TOK + p] = n;
      const int rank = __popc(m & ((1 << e) - 1));
      slot_map[n * KSEL + rank] = gbase + p;
      wrow[gbase + p] = wts[n * NEXP + e];
      ++p;
    }
  }
}

// ---------------- 8-phase GEMM (BM=BN=256, BK=64, 8 waves, dbuf 128 KiB) ----------------
// A [rows,K] bf16 (MODE1: gathered via list; MODE2: compact), Bt [E][Ncols][K] bf16.
// LDS per buf (64 KB): A K-major granules: elem (g*256+r)*8 = A[r][kt*64+g*8..+8], g<8;
// B same at +16384 elems.  Conflict-free: quarter-wave ds_read_b128 = 256B contiguous.
// Iteration = 2 K-tiles (buf0: 2i, buf1: 2i+1), 8 phases; phase = (m-half, k-step).
// Staging: one half-tile (2 GLD/thread) per phase.  P0-P3 stage tile 2i+1 -> buf1
// (its reads ended at prev P7 barrier); P4-P7 stage tile 2i+2 -> buf0 (reads ended P3).
// FIFO wait math: at every fresh phase the needed half-tiles are the 2 oldest of <=4
// outstanding half-tiles -> uniform s_waitcnt vmcnt(4); vmcnt(0) only at last-iter P6.

#define STAGE_HALF(sb, isA, half, kb)                                          \
  { const uint16_t* s_ = (isA) ? aRow : bRow;                                  \
    char* d_ = ldsc + (sb) * 65536 + ((isA) ? 0 : 32768) + wsub * 1024;        \
    const int g0_ = 4 * (half) + whi;                                          \
    GLD16(s_ + (kb) + g0_ * 8, d_ + g0_ * 4096);                               \
    const int g1_ = g0_ + 2;                                                   \
    GLD16(s_ + (kb) + g1_ * 8, d_ + g1_ * 4096); }

#define PHASE(bufR, mh, ks, FRESH, VMZ, DOSTAGE, sb, sIsA, sHalf, kb)          \
  { if (FRESH) {                                                               \
      if (VMZ) asm volatile("s_waitcnt vmcnt(0)" ::: "memory");                \
      else     asm volatile("s_waitcnt vmcnt(4)" ::: "memory");                \
      __builtin_amdgcn_sched_barrier(0);                                       \
    }                                                                          \
    __builtin_amdgcn_s_barrier();                                              \
    __builtin_amdgcn_sched_barrier(0);                                         \
    const int gk_ = (ks) * 4 + qlane;                                          \
    const uint16_t* As_ = lds + (bufR) * 32768 + gk_ * 2048;                   \
    bf16x8 av0 = *(const bf16x8*)(As_ + (size_t)(arow0 + ((mh)*4+0)*16) * 8);  \
    bf16x8 av1 = *(const bf16x8*)(As_ + (size_t)(arow0 + ((mh)*4+1)*16) * 8);  \
    bf16x8 av2 = *(const bf16x8*)(As_ + (size_t)(arow0 + ((mh)*4+2)*16) * 8);  \
    bf16x8 av3 = *(const bf16x8*)(As_ + (size_t)(arow0 + ((mh)*4+3)*16) * 8);  \
    if (FRESH) {                                                               \
      const uint16_t* Bs_ = As_ + 16384;                                       \
      bv[0] = *(const bf16x8*)(Bs_ + (size_t)(brow0 +  0) * 8);                \
      bv[1] = *(const bf16x8*)(Bs_ + (size_t)(brow0 + 16) * 8);                \
      bv[2] = *(const bf16x8*)(Bs_ + (size_t)(brow0 + 32) * 8);                \
      bv[3] = *(const bf16x8*)(Bs_ + (size_t)(brow0 + 48) * 8);                \
    }                                                                          \
    if (DOSTAGE) { STAGE_HALF(sb, sIsA, sHalf, kb); }                          \
    asm volatile("s_waitcnt lgkmcnt(0)" ::: "memory");                         \
    __builtin_amdgcn_sched_barrier(0);                                         \
    __builtin_amdgcn_s_setprio(1);                                             \
    _Pragma("unroll") for (int n_ = 0; n_ < 4; ++n_) {                         \
      acc[(mh)*4+0][n_] = __builtin_amdgcn_mfma_f32_16x16x32_bf16(av0, bv[n_], acc[(mh)*4+0][n_], 0,0,0); \
      acc[(mh)*4+1][n_] = __builtin_amdgcn_mfma_f32_16x16x32_bf16(av1, bv[n_], acc[(mh)*4+1][n_], 0,0,0); \
      acc[(mh)*4+2][n_] = __builtin_amdgcn_mfma_f32_16x16x32_bf16(av2, bv[n_], acc[(mh)*4+2][n_], 0,0,0); \
      acc[(mh)*4+3][n_] = __builtin_amdgcn_mfma_f32_16x16x32_bf16(av3, bv[n_], acc[(mh)*4+3][n_], 0,0,0); \
    }                                                                          \
    __builtin_amdgcn_s_setprio(0); }

template <int MODE>
__launch_bounds__(512, 2)
__global__ void gemm8p_kernel(const uint16_t* __restrict__ A,
                              const uint16_t* __restrict__ Bt,
                              const int* __restrict__ cnt,
                              const int* __restrict__ base,
                              const int* __restrict__ list,
                              const float* __restrict__ wrow,
                              const float* __restrict__ bias,
                              uint16_t* __restrict__ outb,
                              int Kdim, int NI, int Ncols) {
  __shared__ __attribute__((aligned(16))) uint16_t lds[65536];  // 128 KiB, 2 bufs

  const int e  = blockIdx.z;
  const int ce = cnt[e];
  const int tileM = blockIdx.y * 256;
  if (tileM >= ce) return;
  const int be    = base[e];
  const int tileN = blockIdx.x * 256;
  const int tid = threadIdx.x, lane = tid & 63, wid = tid >> 6;
  const int wr = wid >> 2, wc = wid & 3;       // wave tile 128x64 at (wr*128, wc*64)
  const int wsub = wid & 3, whi = wid >> 2;    // staging decomposition
  const int qlane = lane >> 4, l16 = lane & 15;

  // staging source row pointers (thread stages row srow = tid&255)
  const int srow = (wsub << 6) | lane;
  int pA = tileM + srow; pA = pA < ce ? pA : ce - 1;
  const uint16_t* aRow = (MODE == 1)
      ? A + (size_t)list[e * TOK + pA] * Kdim
      : A + (size_t)(be + pA) * Kdim;
  const uint16_t* bRow = Bt + ((size_t)e * Ncols + tileN + srow) * Kdim;
  char* ldsc = (char*)lds;

  const int arow0 = wr * 128 + l16;
  const int brow0 = wc * 64 + l16;

  f32x4 acc[8][4];
#pragma unroll
  for (int m = 0; m < 8; ++m)
#pragma unroll
    for (int n = 0; n < 4; ++n) acc[m][n] = (f32x4){0.f, 0.f, 0.f, 0.f};
  bf16x8 bv[4];

  // prologue: tile 0 -> buf0, order Ah0, Bh0, Ah1, Bh1 (FIFO oldest-first)
  STAGE_HALF(0, 1, 0, 0);
  STAGE_HALF(0, 0, 0, 0);
  STAGE_HALF(0, 1, 1, 0);
  STAGE_HALF(0, 0, 1, 0);

  for (int i = 0; i < NI; ++i) {
    const int kb1 = (2 * i + 1) * 64;
    const int kb2 = (2 * i + 2) * 64;
    const bool st2   = (i + 1 < NI);
    const bool lastI = (i + 1 == NI);
    // tile 2i in buf0; stage tile 2i+1 -> buf1
    PHASE(0, 0, 0, 1, false, true, 1, 1, 0, kb1)   // P0
    PHASE(0, 1, 0, 0, false, true, 1, 0, 0, kb1)   // P1
    PHASE(0, 1, 1, 1, false, true, 1, 1, 1, kb1)   // P2
    PHASE(0, 0, 1, 0, false, true, 1, 0, 1, kb1)   // P3
    // tile 2i+1 in buf1; stage tile 2i+2 -> buf0
    PHASE(1, 0, 0, 1, false, st2, 0, 1, 0, kb2)    // P4
    PHASE(1, 1, 0, 0, false, st2, 0, 0, 0, kb2)    // P5
    PHASE(1, 1, 1, 1, lastI, st2, 0, 1, 1, kb2)    // P6
    PHASE(1, 0, 1, 0, false, st2, 0, 0, 1, kb2)    // P7
  }

  // ---- epilogue ----
  if (MODE == 1) {
    const float* b1e = bias + (size_t)e * Ncols;
#pragma unroll
    for (int m = 0; m < 8; ++m)
#pragma unroll
      for (int r = 0; r < 4; ++r) {
        const int p = tileM + wr * 128 + m * 16 + (qlane << 2) + r;
        if (p < ce) {
          const float w = wrow[be + p];
          uint16_t* orow = outb + (size_t)(be + p) * Ncols;
#pragma unroll
          for (int n = 0; n < 4; ++n) {
            const int col = tileN + wc * 64 + n * 16 + l16;
            float v = acc[m][n][r] + b1e[col];
            v = v > 0.f ? v : 0.f;
            orow[col] = f2bf(v * w);
          }
        }
      }
  } else {
#pragma unroll
    for (int m = 0; m < 8; ++m)
#pragma unroll
      for (int r = 0; r < 4; ++r) {
        const int p = tileM + wr * 128 + m * 16 + (qlane << 2) + r;
        if (p < ce) {
          uint16_t* orow = outb + (size_t)(be + p) * Ncols;
#pragma unroll
          for (int n = 0; n < 4; ++n) {
            const int col = tileN + wc * 64 + n * 16 + l16;
            orow[col] = f2bf(acc[m][n][r]);
          }
        }
      }
  }
}

// ---------------- reduce: out[n,:] = sum_e w*b2[e,:] + sum_{k<5} obuf[slot_k,:] ----------------

__global__ void reduce_kernel(const uint16_t* __restrict__ obuf,
                              const int* __restrict__ slot_map,
                              const float* __restrict__ wts,
                              const float* __restrict__ b2,
                              float* __restrict__ out) {
  const int n = blockIdx.x;
  const int t = threadIdx.x;            // 256
  const int c = t * 8;                  // 8 cols per thread

  int slots[KSEL];
#pragma unroll
  for (int k = 0; k < KSEL; ++k) slots[k] = slot_map[n * KSEL + k];
  float w8[NEXP];
#pragma unroll
  for (int e = 0; e < NEXP; ++e) w8[e] = wts[n * NEXP + e];

  float s[8];
#pragma unroll
  for (int j = 0; j < 8; ++j) s[j] = 0.f;
#pragma unroll
  for (int e = 0; e < NEXP; ++e) {
    const float4 b0 = *(const float4*)(b2 + (size_t)e * ODIM + c);
    const float4 b1v = *(const float4*)(b2 + (size_t)e * ODIM + c + 4);
    s[0] += w8[e] * b0.x; s[1] += w8[e] * b0.y; s[2] += w8[e] * b0.z; s[3] += w8[e] * b0.w;
    s[4] += w8[e] * b1v.x; s[5] += w8[e] * b1v.y; s[6] += w8[e] * b1v.z; s[7] += w8[e] * b1v.w;
  }
#pragma unroll
  for (int k = 0; k < KSEL; ++k) {
    const ushort8 v = *(const ushort8*)(obuf + (size_t)slots[k] * ODIM + c);
#pragma unroll
    for (int j = 0; j < 8; ++j) s[j] += bf2f(v[j]);
  }
  float4 o0 = make_float4(s[0], s[1], s[2], s[3]);
  float4 o1 = make_float4(s[4], s[5], s[6], s[7]);
  *(float4*)(out + (size_t)n * ODIM + c) = o0;
  *(float4*)(out + (size_t)n * ODIM + c + 4) = o1;
}

// ---------------- launch ----------------

extern "C" void kernel_launch(void* const* d_in, const int* in_sizes, int n_in,
                              void* d_out, int out_size, void* d_ws, size_t ws_size,
                              hipStream_t stream) {
  const float* x    = (const float*)d_in[0];
  const float* Wg   = (const float*)d_in[1];
  const float* bg   = (const float*)d_in[2];
  const float* Wa   = (const float*)d_in[3];
  const float* ba   = (const float*)d_in[4];
  const float* Wb   = (const float*)d_in[5];
  const float* bb   = (const float*)d_in[6];
  const float* sigs = (const float*)d_in[7];
  const float* W1   = (const float*)d_in[8];
  const float* b1   = (const float*)d_in[9];
  const float* W2   = (const float*)d_in[10];
  const float* b2   = (const float*)d_in[11];
  float* out = (float*)d_out;

  char* ws = (char*)d_ws;
  float*    wts     = (float*)(ws + 0);           //   131072 B
  int*      selmask = (int*)(ws + 131072);        //    16384 B
  int*      cnt     = (int*)(ws + 147456);        //       32 B
  int*      base    = (int*)(ws + 147584);        //       32 B
  int*      slot_map= (int*)(ws + 151552);        //    81920 B
  float*    wrow    = (float*)(ws + 233472);      //    81920 B
  int*      list    = (int*)(ws + 315392);        //   131072 B -> 446464
  uint16_t* xbf     = (uint16_t*)(ws + 446464);   //  16777216 B -> 17223680
  uint16_t* W1T     = (uint16_t*)(ws + 17223680); // 134217728 B -> 151441408
  uint16_t* W2T     = (uint16_t*)(ws + 151441408);// 134217728 B -> 285659136
  uint16_t* hbuf    = (uint16_t*)(ws + 285659136);// 167772160 B -> 453431296
  uint16_t* obuf    = (uint16_t*)(ws + 453431296);//  83886080 B -> 537317376 (512.4 MB)

  cast_x_kernel<<<(TOK * DIM / 4) / 256, 256, 0, stream>>>(x, xbf, TOK * DIM / 4);
  // W1 [E][D][H] -> W1T [E][H][D]
  transpose_cast_kernel<<<dim3(HID / 32, DIM / 32, NEXP), dim3(32, 8), 0, stream>>>(
      W1, W1T, DIM, HID, (long)DIM * HID, (long)DIM * HID);
  // W2 [E][H][O] -> W2T [E][O][H]
  transpose_cast_kernel<<<dim3(ODIM / 32, HID / 32, NEXP), dim3(32, 8), 0, stream>>>(
      W2, W2T, HID, ODIM, (long)HID * ODIM, (long)ODIM * HID);
  routing_kernel<<<TOK, 64, 0, stream>>>(x, Wg, bg, Wa, ba, Wb, bb, sigs, wts, selmask);
  listbuild_kernel<<<NEXP, 256, 0, stream>>>(selmask, wts, cnt, base, list, slot_map, wrow);

  // gemm1: hbuf[be+p, col] = bf16( wrow * relu( x[list[p],:] @ W1[e][:,col] + b1[e,col] ) )
  gemm8p_kernel<1><<<dim3(HID / 256, TOK / 256, NEXP), 512, 0, stream>>>(
      xbf, W1T, cnt, base, list, wrow, b1, hbuf, DIM, DIM / 128, HID);
  // gemm2: obuf[be+p, col] = bf16( hbuf[be+p, :] @ W2[e][:, col] )
  gemm8p_kernel<2><<<dim3(ODIM / 256, TOK / 256, NEXP), 512, 0, stream>>>(
      hbuf, W2T, cnt, base, nullptr, nullptr, nullptr, obuf, HID, HID / 128, ODIM);
  reduce_kernel<<<TOK, 256, 0, stream>>>(obuf, slot_map, wts, b2, out);
}